// Round 4
// baseline (1887.022 us; speedup 1.0000x reference)
//
#include <hip/hip_runtime.h>
#include <hip/hip_bf16.h>
#include <hip/hip_fp16.h>

#define E_ 16
#define T_ 128

typedef _Float16 h2_t __attribute__((ext_vector_type(2)));

__device__ __forceinline__ float fdot2u(uint32_t w, uint32_t h, float acc) {
#if __has_builtin(__builtin_amdgcn_fdot2)
  return __builtin_amdgcn_fdot2(__builtin_bit_cast(h2_t, w),
                                __builtin_bit_cast(h2_t, h), acc, false);
#else
  h2_t wv = __builtin_bit_cast(h2_t, w), hv = __builtin_bit_cast(h2_t, h);
  return acc + (float)wv.x * (float)hv.x + (float)wv.y * (float)hv.y;
#endif
}

__device__ __forceinline__ uint32_t rdlane(uint32_t v, int l) {
  return (uint32_t)__builtin_amdgcn_readlane((int)v, l);
}

__device__ __forceinline__ uint32_t packh2(float a, float b) {
  h2_t p; p.x = (_Float16)a; p.y = (_Float16)b;
  return __builtin_bit_cast(uint32_t, p);
}

__device__ __forceinline__ float apply_act(float v, int act) {
  if (act == 1) return tanhf(v);
  if (act == 2) { // jax.nn.gelu approximate=True
    const float c = 0.7978845608028654f;
    return 0.5f * v * (1.0f + tanhf(c * (v + 0.044715f * v * v * v)));
  }
  return v;
}

// ---- skinny GEMM: C[128,N] = act(A[128,K] @ W[K,N] + bias), batched over e (grid.y), split-K (grid.z) ----
__global__ void __launch_bounds__(256) gemm_skinny(
    const float* __restrict__ A, const float* __restrict__ W,
    const float* __restrict__ bias, float* __restrict__ C, float* __restrict__ part,
    int N, int K, int lda, int ldc,
    long sAe, long sWe, long sBe, long sCe,
    int S, int act)
{
  int n0 = blockIdx.x * 64;
  int e  = blockIdx.y;
  int s  = blockIdx.z;
  const float* Ae = A + (long)e * sAe;
  const float* We = W + (long)e * sWe + n0;
  int kper = K / S;
  int kb = s * kper, ke = kb + kper;

  __shared__ float As[32][132];   // A-chunk transposed: As[kk][m], pad 4
  __shared__ float Ws[32][68];    // W-chunk: Ws[kk][n], pad 4
  int tid = threadIdx.x;
  int tn = tid & 15, tm = tid >> 4;
  float acc[8][4];
  #pragma unroll
  for (int i = 0; i < 8; ++i)
    #pragma unroll
    for (int j = 0; j < 4; ++j) acc[i][j] = 0.f;

  for (int k0 = kb; k0 < ke; k0 += 32) {
    #pragma unroll
    for (int i = 0; i < 4; ++i) {
      int li = i * 1024 + tid * 4;
      int r = li >> 5, kk = li & 31;
      float4 a4 = *(const float4*)(Ae + (long)r * lda + k0 + kk);
      As[kk+0][r] = a4.x; As[kk+1][r] = a4.y; As[kk+2][r] = a4.z; As[kk+3][r] = a4.w;
    }
    #pragma unroll
    for (int i = 0; i < 2; ++i) {
      int li = i * 1024 + tid * 4;
      int kk = li >> 6, j = li & 63;
      *(float4*)&Ws[kk][j] = *(const float4*)(We + (long)(k0 + kk) * N + j);
    }
    __syncthreads();
    #pragma unroll
    for (int kk = 0; kk < 32; ++kk) {
      float4 a0 = *(const float4*)&As[kk][tm*8];
      float4 a1 = *(const float4*)&As[kk][tm*8+4];
      float4 w4 = *(const float4*)&Ws[kk][tn*4];
      float av[8] = {a0.x,a0.y,a0.z,a0.w,a1.x,a1.y,a1.z,a1.w};
      float wv[4] = {w4.x,w4.y,w4.z,w4.w};
      #pragma unroll
      for (int i2 = 0; i2 < 8; ++i2)
        #pragma unroll
        for (int j2 = 0; j2 < 4; ++j2)
          acc[i2][j2] = fmaf(av[i2], wv[j2], acc[i2][j2]);
    }
    __syncthreads();
  }

  if (S == 1) {
    #pragma unroll
    for (int i2 = 0; i2 < 8; ++i2) {
      int r = tm * 8 + i2;
      float4 o; float* op = (float*)&o;
      #pragma unroll
      for (int j2 = 0; j2 < 4; ++j2)
        op[j2] = apply_act(acc[i2][j2] + bias[(long)e*sBe + n0 + tn*4 + j2], act);
      *(float4*)(C + (long)e*sCe + (long)r*ldc + n0 + tn*4) = o;
    }
  } else {
    float* pp = part + ((long)(s * gridDim.y + e) * 128) * N;
    #pragma unroll
    for (int i2 = 0; i2 < 8; ++i2) {
      int r = tm * 8 + i2;
      float4 o; float* op = (float*)&o;
      #pragma unroll
      for (int j2 = 0; j2 < 4; ++j2) op[j2] = acc[i2][j2];
      *(float4*)(pp + (long)r * N + n0 + tn*4) = o;
    }
  }
}

// reduce split-K partials + bias + act -> C
__global__ void __launch_bounds__(256) reduce_ep(
    const float* __restrict__ part, const float* __restrict__ bias, float* __restrict__ C,
    int S, int N, int ldc, long sBe, long sCe, int act, int total, int Eb)
{
  int idx = blockIdx.x * 256 + threadIdx.x;
  if (idx >= total) return;
  int n = idx % N;
  int r = (idx / N) & 127;
  int e = idx / (N * 128);
  long sstride = (long)Eb * 128 * N;
  float v = 0.f;
  for (int s = 0; s < S; ++s) v += part[s * sstride + ((long)e * 128 + r) * N + n];
  v = apply_act(v + bias[(long)e * sBe + n], act);
  C[(long)e * sCe + (long)r * ldc + n] = v;
}

// ---- sequential RNN layer: h[t] = tanh(P[t] + h[t-1] @ Wh) ----
// ONE workgroup per encoder (grid=16, block=512). Thread owns output column j=tid.
// Weights fp16-packed: 192 pairs in VGPRs + 64 pairs in LDS (128 KB).
// h broadcast WITHOUT LDS re-reads: each thread does ONE ds_read_b128 (lane l
// picks up h-pairs 4l..4l+3), then v_readlane broadcasts pair (4L+r) from
// lane L of the same wave; dot2 consumes the SGPR directly. 17 LDS reads/step
// (was 78). No __launch_bounds__ — amdgpu_waves_per_eu(2,2) alone grants the
// full 256-VGPR budget (rounds 2-3: launch_bounds conflicted, alloc capped at
// 128 and spilled ~11 MB/dispatch of scratch).
#define NRP 192   // weight pairs in VGPRs
#define NLG 16    // LDS weight groups (4 pairs each) -> 64 pairs, 131072 B

__global__ void __attribute__((amdgpu_flat_work_group_size(512, 512)))
__attribute__((amdgpu_waves_per_eu(2, 2)))
rnn_seq(
    const float* __restrict__ P,     // [T][E][512], pre-activation incl. bias
    const float* __restrict__ Wh,    // + e*sWe : [512][512]
    float* __restrict__ H,           // (t*E+e)*1536 + col  (layer offset applied by caller)
    long sWe)
{
  extern __shared__ uint32_t smem[];
  uint32_t* lw  = smem;                  // [NLG][512][4] uints = 128 KB
  uint32_t* hb2 = smem + NLG * 2048;     // 2 x 256 uints (512 fp16 each)

  int e = blockIdx.x;
  int col = threadIdx.x;
  int lane = col & 63;
  const float* W = Wh + (long)e * sWe + col;

  // weights: pairs 0..191 -> VGPR, pairs 192..255 -> LDS (lane 48+g supplies group g)
  uint32_t w2[NRP];
  #pragma unroll
  for (int p = 0; p < NRP; ++p)
    w2[p] = packh2(W[(long)(2 * p) * 512], W[(long)(2 * p + 1) * 512]);
  for (int g = 0; g < NLG; ++g) {
    uint4 v;
    v.x = packh2(W[(long)(2*(NRP + 4*g + 0)) * 512], W[(long)(2*(NRP + 4*g + 0) + 1) * 512]);
    v.y = packh2(W[(long)(2*(NRP + 4*g + 1)) * 512], W[(long)(2*(NRP + 4*g + 1) + 1) * 512]);
    v.z = packh2(W[(long)(2*(NRP + 4*g + 2)) * 512], W[(long)(2*(NRP + 4*g + 2) + 1) * 512]);
    v.w = packh2(W[(long)(2*(NRP + 4*g + 3)) * 512], W[(long)(2*(NRP + 4*g + 3) + 1) * 512]);
    *(uint4*)(lw + ((long)g * 512 + col) * 4) = v;
  }
  if (col < 256) hb2[col] = 0;   // h(-1) = 0 in buffer 0
  __syncthreads();

  for (int t = 0; t < T_; ++t) {
    float p = P[((long)t * E_ + e) * 512 + col];
    // this thread's slice of h(t-1): pairs 4*lane .. 4*lane+3
    uint4 hr = *(const uint4*)(hb2 + (t & 1) * 256 + lane * 4);
    float a0 = 0.f, a1 = 0.f, a2 = 0.f, a3 = 0.f;
    #pragma unroll
    for (int L = 0; L < 48; ++L) {   // pairs 0..191 from VGPR weights
      a0 = fdot2u(w2[4*L+0], rdlane(hr.x, L), a0);
      a1 = fdot2u(w2[4*L+1], rdlane(hr.y, L), a1);
      a2 = fdot2u(w2[4*L+2], rdlane(hr.z, L), a2);
      a3 = fdot2u(w2[4*L+3], rdlane(hr.w, L), a3);
    }
    #pragma unroll
    for (int g = 0; g < NLG; ++g) {  // pairs 192..255 from LDS weights
      uint4 w4 = *(const uint4*)(lw + (g * 512 + col) * 4);
      int L = 48 + g;
      a0 = fdot2u(w4.x, rdlane(hr.x, L), a0);
      a1 = fdot2u(w4.y, rdlane(hr.y, L), a1);
      a2 = fdot2u(w4.z, rdlane(hr.z, L), a2);
      a3 = fdot2u(w4.w, rdlane(hr.w, L), a3);
    }
    float v = tanhf((a0 + a1) + (a2 + a3) + p);
    H[((long)t * E_ + e) * 1536 + col] = v;
    _Float16* hw = (_Float16*)(hb2 + ((t + 1) & 1) * 256);
    hw[col] = (_Float16)v;
    __syncthreads();
  }
}

extern "C" void kernel_launch(void* const* d_in, const int* in_sizes, int n_in,
                              void* d_out, int out_size, void* d_ws, size_t ws_size,
                              hipStream_t stream)
{
  const float* x      = (const float*)d_in[0];
  const float* W_in0  = (const float*)d_in[1];
  const float* Wh0    = (const float*)d_in[2];
  const float* b0     = (const float*)d_in[3];
  const float* W_inr  = (const float*)d_in[4];
  const float* Wh_r   = (const float*)d_in[5];
  const float* b_r    = (const float*)d_in[6];
  const float* W_ff1  = (const float*)d_in[7];
  const float* b_ff1  = (const float*)d_in[8];
  const float* W_ff2  = (const float*)d_in[9];
  const float* b_ff2  = (const float*)d_in[10];
  const float* W_d0   = (const float*)d_in[11];
  const float* b_d0   = (const float*)d_in[12];
  const float* W_dmid = (const float*)d_in[13];
  const float* b_dmid = (const float*)d_in[14];
  const float* W_dout = (const float*)d_in[15];
  const float* b_dout = (const float*)d_in[16];
  float* ws = (float*)d_ws;

  // workspace layout (floats)
  float* h    = ws;                    // [T][E][3][512]  3,145,728
  float* P    = ws + 3145728;          // [T][E][512]     1,048,576
  float* FF   = ws + 4194304;          // [T][E][2048]    4,194,304
  float* ENC  = ws + 8388608;          // [T][E*512]      1,048,576
  float* Z0   = ws + 9437184;          // [128][2048]       262,144
  float* Z1   = ws + 9699328;
  float* Z2   = ws + 9961472;
  float* PART = ws + 10223616;         // split-K partials 2,097,152

  (void)in_sizes; (void)n_in; (void)out_size; (void)ws_size;

  dim3 blk(256);
  const size_t rnn_lds = (size_t)(NLG * 2048 + 512) * 4;  // 133,120 B

  // P = x @ W_in0 + b0
  gemm_skinny<<<dim3(8,16,1), blk, 0, stream>>>(x, W_in0, b0, P, PART,
      512, 32, 32, 8192, 0L, 16384L, 512L, 512L, 1, 0);
  // layer 0 recurrence
  rnn_seq<<<dim3(16), dim3(512), rnn_lds, stream>>>(P, Wh0, h, 262144L);
  // P = h0 @ W_in_rest[:,0] + b_rest[:,0]
  gemm_skinny<<<dim3(8,16,1), blk, 0, stream>>>(h, W_inr, b_r, P, PART,
      512, 512, 24576, 8192, 1536L, 524288L, 1024L, 512L, 1, 0);
  rnn_seq<<<dim3(16), dim3(512), rnn_lds, stream>>>(P, Wh_r, h + 512, 524288L);
  // P = h1 @ W_in_rest[:,1] + b_rest[:,1]
  gemm_skinny<<<dim3(8,16,1), blk, 0, stream>>>(h + 512, W_inr + 262144, b_r + 512, P, PART,
      512, 512, 24576, 8192, 1536L, 524288L, 1024L, 512L, 1, 0);
  rnn_seq<<<dim3(16), dim3(512), rnn_lds, stream>>>(P, Wh_r + 262144, h + 1024, 524288L);
  // FF1: gelu(cat @ W_ff1 + b_ff1)
  gemm_skinny<<<dim3(32,16,1), blk, 0, stream>>>(h, W_ff1, b_ff1, FF, PART,
      2048, 1536, 24576, 32768, 1536L, 3145728L, 2048L, 2048L, 1, 2);
  // FF2 (split-2): ENC = FF @ W_ff2 + b_ff2
  gemm_skinny<<<dim3(8,16,2), blk, 0, stream>>>(FF, W_ff2, b_ff2, ENC, PART,
      512, 2048, 32768, 8192, 2048L, 1048576L, 512L, 512L, 2, 0);
  reduce_ep<<<dim3(4096), blk, 0, stream>>>(PART, b_ff2, ENC,
      2, 512, 8192, 512L, 512L, 0, 16*128*512, 16);
  // decoder: Z0 = tanh(ENC @ W_d0 + b_d0)   (split-8)
  gemm_skinny<<<dim3(32,1,8), blk, 0, stream>>>(ENC, W_d0, b_d0, Z0, PART,
      2048, 8192, 8192, 2048, 0L, 0L, 0L, 0L, 8, 0);
  reduce_ep<<<dim3(1024), blk, 0, stream>>>(PART, b_d0, Z0,
      8, 2048, 2048, 0L, 0L, 1, 128*2048, 1);
  // Z1 = tanh(Z0 @ W_dmid[0] + b_dmid[0])
  gemm_skinny<<<dim3(32,1,8), blk, 0, stream>>>(Z0, W_dmid, b_dmid, Z1, PART,
      2048, 2048, 2048, 2048, 0L, 0L, 0L, 0L, 8, 0);
  reduce_ep<<<dim3(1024), blk, 0, stream>>>(PART, b_dmid, Z1,
      8, 2048, 2048, 0L, 0L, 1, 128*2048, 1);
  // Z2 = tanh(Z1 @ W_dmid[1] + b_dmid[1])
  gemm_skinny<<<dim3(32,1,8), blk, 0, stream>>>(Z1, W_dmid + 4194304, b_dmid + 2048, Z2, PART,
      2048, 2048, 2048, 2048, 0L, 0L, 0L, 0L, 8, 0);
  reduce_ep<<<dim3(1024), blk, 0, stream>>>(PART, b_dmid + 2048, Z2,
      8, 2048, 2048, 0L, 0L, 1, 128*2048, 1);
  // Y = Z2 @ W_dout + b_dout -> d_out [1,128,1024]
  gemm_skinny<<<dim3(16,1,8), blk, 0, stream>>>(Z2, W_dout, b_dout, (float*)d_out, PART,
      1024, 2048, 2048, 1024, 0L, 0L, 0L, 0L, 8, 0);
  reduce_ep<<<dim3(512), blk, 0, stream>>>(PART, b_dout, (float*)d_out,
      8, 1024, 1024, 0L, 0L, 0, 128*1024, 1);
}

// Round 5
// 1636.694 us; speedup vs baseline: 1.1529x; 1.1529x over previous
//
#include <hip/hip_runtime.h>
#include <hip/hip_bf16.h>
#include <hip/hip_fp16.h>

#define E_ 16
#define T_ 128

typedef _Float16 h2_t __attribute__((ext_vector_type(2)));

__device__ __forceinline__ float fdot2u(uint32_t w, uint32_t h, float acc) {
#if __has_builtin(__builtin_amdgcn_fdot2)
  return __builtin_amdgcn_fdot2(__builtin_bit_cast(h2_t, w),
                                __builtin_bit_cast(h2_t, h), acc, false);
#else
  h2_t wv = __builtin_bit_cast(h2_t, w), hv = __builtin_bit_cast(h2_t, h);
  return acc + (float)wv.x * (float)hv.x + (float)wv.y * (float)hv.y;
#endif
}

__device__ __forceinline__ uint32_t rdlane(uint32_t v, int l) {
  return (uint32_t)__builtin_amdgcn_readlane((int)v, l);
}

__device__ __forceinline__ uint32_t packh2(float a, float b) {
  h2_t p; p.x = (_Float16)a; p.y = (_Float16)b;
  return __builtin_bit_cast(uint32_t, p);
}

__device__ __forceinline__ float apply_act(float v, int act) {
  if (act == 1) return tanhf(v);
  if (act == 2) { // jax.nn.gelu approximate=True
    const float c = 0.7978845608028654f;
    return 0.5f * v * (1.0f + tanhf(c * (v + 0.044715f * v * v * v)));
  }
  return v;
}

// ---- skinny GEMM: C[128,N] = act(A[128,K] @ W[K,N] + bias), batched over e (grid.y), split-K (grid.z) ----
__global__ void __launch_bounds__(256) gemm_skinny(
    const float* __restrict__ A, const float* __restrict__ W,
    const float* __restrict__ bias, float* __restrict__ C, float* __restrict__ part,
    int N, int K, int lda, int ldc,
    long sAe, long sWe, long sBe, long sCe,
    int S, int act)
{
  int n0 = blockIdx.x * 64;
  int e  = blockIdx.y;
  int s  = blockIdx.z;
  const float* Ae = A + (long)e * sAe;
  const float* We = W + (long)e * sWe + n0;
  int kper = K / S;
  int kb = s * kper, ke = kb + kper;

  __shared__ float As[32][132];   // A-chunk transposed: As[kk][m], pad 4
  __shared__ float Ws[32][68];    // W-chunk: Ws[kk][n], pad 4
  int tid = threadIdx.x;
  int tn = tid & 15, tm = tid >> 4;
  float acc[8][4];
  #pragma unroll
  for (int i = 0; i < 8; ++i)
    #pragma unroll
    for (int j = 0; j < 4; ++j) acc[i][j] = 0.f;

  for (int k0 = kb; k0 < ke; k0 += 32) {
    #pragma unroll
    for (int i = 0; i < 4; ++i) {
      int li = i * 1024 + tid * 4;
      int r = li >> 5, kk = li & 31;
      float4 a4 = *(const float4*)(Ae + (long)r * lda + k0 + kk);
      As[kk+0][r] = a4.x; As[kk+1][r] = a4.y; As[kk+2][r] = a4.z; As[kk+3][r] = a4.w;
    }
    #pragma unroll
    for (int i = 0; i < 2; ++i) {
      int li = i * 1024 + tid * 4;
      int kk = li >> 6, j = li & 63;
      *(float4*)&Ws[kk][j] = *(const float4*)(We + (long)(k0 + kk) * N + j);
    }
    __syncthreads();
    #pragma unroll
    for (int kk = 0; kk < 32; ++kk) {
      float4 a0 = *(const float4*)&As[kk][tm*8];
      float4 a1 = *(const float4*)&As[kk][tm*8+4];
      float4 w4 = *(const float4*)&Ws[kk][tn*4];
      float av[8] = {a0.x,a0.y,a0.z,a0.w,a1.x,a1.y,a1.z,a1.w};
      float wv[4] = {w4.x,w4.y,w4.z,w4.w};
      #pragma unroll
      for (int i2 = 0; i2 < 8; ++i2)
        #pragma unroll
        for (int j2 = 0; j2 < 4; ++j2)
          acc[i2][j2] = fmaf(av[i2], wv[j2], acc[i2][j2]);
    }
    __syncthreads();
  }

  if (S == 1) {
    #pragma unroll
    for (int i2 = 0; i2 < 8; ++i2) {
      int r = tm * 8 + i2;
      float4 o; float* op = (float*)&o;
      #pragma unroll
      for (int j2 = 0; j2 < 4; ++j2)
        op[j2] = apply_act(acc[i2][j2] + bias[(long)e*sBe + n0 + tn*4 + j2], act);
      *(float4*)(C + (long)e*sCe + (long)r*ldc + n0 + tn*4) = o;
    }
  } else {
    float* pp = part + ((long)(s * gridDim.y + e) * 128) * N;
    #pragma unroll
    for (int i2 = 0; i2 < 8; ++i2) {
      int r = tm * 8 + i2;
      float4 o; float* op = (float*)&o;
      #pragma unroll
      for (int j2 = 0; j2 < 4; ++j2) op[j2] = acc[i2][j2];
      *(float4*)(pp + (long)r * N + n0 + tn*4) = o;
    }
  }
}

// reduce split-K partials + bias + act -> C
__global__ void __launch_bounds__(256) reduce_ep(
    const float* __restrict__ part, const float* __restrict__ bias, float* __restrict__ C,
    int S, int N, int ldc, long sBe, long sCe, int act, int total, int Eb)
{
  int idx = blockIdx.x * 256 + threadIdx.x;
  if (idx >= total) return;
  int n = idx % N;
  int r = (idx / N) & 127;
  int e = idx / (N * 128);
  long sstride = (long)Eb * 128 * N;
  float v = 0.f;
  for (int s = 0; s < S; ++s) v += part[s * sstride + ((long)e * 128 + r) * N + n];
  v = apply_act(v + bias[(long)e * sBe + n], act);
  C[(long)e * sCe + (long)r * ldc + n] = v;
}

// ---- sequential RNN layer: h[t] = tanh(P[t] + h[t-1] @ Wh) ----
// ONE workgroup per encoder, block = 1024 (16 waves). Wave w: khalf = w>>3
// (which half of K this wave covers), cols 64*(w&7)..+63 (lane = col offset).
// Thread owns one output column x one K-half = 128 fp16 weight pairs:
// 92 in VGPRs + 36 in LDS (144 KB). 128-VGPR cap (forced by 16 waves/CU) is
// genuinely sufficient -> no spill by construction (rounds 2-4 spilled ~10 MB
// per dispatch because 256 pairs/thread could never fit).
// khalf is wave-uniform, so h broadcast = ONE ds_read_b64/thread (distributed
// pairs) + v_readlane -> SGPR operand of v_dot2_f32_f16. Cross-half reduce via
// 4 B LDS partial + barrier. 2 barriers/step, h single-buffered in LDS fp16.
#define RNN_VP 92   // weight pairs in VGPRs per thread
#define RNN_LG 9    // uint4 LDS weight groups per thread (36 pairs, 147456 B)

__global__ void __launch_bounds__(1024)
rnn_seq(
    const float* __restrict__ P,     // [T][E][512], pre-activation incl. bias
    const float* __restrict__ Wh,    // + e*sWe : [512][512]
    float* __restrict__ H,           // (t*E+e)*1536 + col  (layer offset applied by caller)
    long sWe)
{
  extern __shared__ uint32_t smem[];
  uint32_t* lw   = smem;                       // [RNN_LG][1024][4] uints = 147456 B
  uint32_t* hbuf = smem + RNN_LG * 4096;       // 256 uints = 512 fp16
  float*    red  = (float*)(hbuf + 256);       // 512 floats (khalf-1 partials)

  int tid  = threadIdx.x;
  int lane = tid & 63;
  int wid  = tid >> 6;
  int kh   = wid >> 3;               // K-half: 0/1 (wave-uniform)
  int col  = (wid & 7) * 64 + lane;  // output column 0..511
  int e    = blockIdx.x;

  const float* W = Wh + (long)e * sWe + col;   // element (k,col) at W[k*512]

  // pair q (0..127) of this thread covers k = 256*kh + 2q, 2q+1
  uint32_t w2[RNN_VP];
  #pragma unroll
  for (int q = 0; q < RNN_VP; ++q) {
    int k = 256 * kh + 2 * q;
    w2[q] = packh2(W[(long)k * 512], W[(long)(k + 1) * 512]);
  }
  for (int g = 0; g < RNN_LG; ++g) {
    int k0 = 256 * kh + 2 * (RNN_VP + 4 * g);
    uint4 v;
    v.x = packh2(W[(long)(k0 + 0) * 512], W[(long)(k0 + 1) * 512]);
    v.y = packh2(W[(long)(k0 + 2) * 512], W[(long)(k0 + 3) * 512]);
    v.z = packh2(W[(long)(k0 + 4) * 512], W[(long)(k0 + 5) * 512]);
    v.w = packh2(W[(long)(k0 + 6) * 512], W[(long)(k0 + 7) * 512]);
    *(uint4*)(lw + ((long)g * 1024 + tid) * 4) = v;
  }
  if (tid < 256) hbuf[tid] = 0;      // h(-1) = 0
  __syncthreads();

  for (int t = 0; t < T_; ++t) {
    // distributed h slice: lane L holds pairs 128*kh + {2L, 2L+1}
    uint2 hr = *(const uint2*)(hbuf + 128 * kh + 2 * lane);
    float p = (kh == 0) ? P[((long)t * E_ + e) * 512 + col] : 0.f;
    float a0 = 0.f, a1 = 0.f, a2 = 0.f, a3 = 0.f;
    // pairs q=0..91 from VGPR weights; broadcast source lane L = q>>1
    #pragma unroll
    for (int L = 0; L < RNN_VP / 2; ++L) {
      a0 = fdot2u(w2[2 * L + 0], rdlane(hr.x, L), a0);
      a1 = fdot2u(w2[2 * L + 1], rdlane(hr.y, L), a1);
    }
    // pairs q=92..127 from LDS weights
    #pragma unroll
    for (int g = 0; g < RNN_LG; ++g) {
      uint4 w4 = *(const uint4*)(lw + (g * 1024 + tid) * 4);
      int L0 = RNN_VP / 2 + 2 * g;
      a2 = fdot2u(w4.x, rdlane(hr.x, L0), a2);
      a3 = fdot2u(w4.y, rdlane(hr.y, L0), a3);
      a2 = fdot2u(w4.z, rdlane(hr.x, L0 + 1), a2);
      a3 = fdot2u(w4.w, rdlane(hr.y, L0 + 1), a3);
    }
    float s = (a0 + a1) + (a2 + a3);
    if (kh) red[col] = s;
    __syncthreads();                 // partials ready; all hbuf reads done
    if (!kh) {
      float v = tanhf(s + red[col] + p);
      H[((long)t * E_ + e) * 1536 + col] = v;
      ((_Float16*)hbuf)[col] = (_Float16)v;
    }
    __syncthreads();                 // new h visible for next step
  }
}

extern "C" void kernel_launch(void* const* d_in, const int* in_sizes, int n_in,
                              void* d_out, int out_size, void* d_ws, size_t ws_size,
                              hipStream_t stream)
{
  const float* x      = (const float*)d_in[0];
  const float* W_in0  = (const float*)d_in[1];
  const float* Wh0    = (const float*)d_in[2];
  const float* b0     = (const float*)d_in[3];
  const float* W_inr  = (const float*)d_in[4];
  const float* Wh_r   = (const float*)d_in[5];
  const float* b_r    = (const float*)d_in[6];
  const float* W_ff1  = (const float*)d_in[7];
  const float* b_ff1  = (const float*)d_in[8];
  const float* W_ff2  = (const float*)d_in[9];
  const float* b_ff2  = (const float*)d_in[10];
  const float* W_d0   = (const float*)d_in[11];
  const float* b_d0   = (const float*)d_in[12];
  const float* W_dmid = (const float*)d_in[13];
  const float* b_dmid = (const float*)d_in[14];
  const float* W_dout = (const float*)d_in[15];
  const float* b_dout = (const float*)d_in[16];
  float* ws = (float*)d_ws;

  // workspace layout (floats)
  float* h    = ws;                    // [T][E][3][512]  3,145,728
  float* P    = ws + 3145728;          // [T][E][512]     1,048,576
  float* FF   = ws + 4194304;          // [T][E][2048]    4,194,304
  float* ENC  = ws + 8388608;          // [T][E*512]      1,048,576
  float* Z0   = ws + 9437184;          // [128][2048]       262,144
  float* Z1   = ws + 9699328;
  float* Z2   = ws + 9961472;
  float* PART = ws + 10223616;         // split-K partials 2,097,152

  (void)in_sizes; (void)n_in; (void)out_size; (void)ws_size;

  dim3 blk(256);
  const size_t rnn_lds = (size_t)(RNN_LG * 4096 + 256) * 4 + 512 * 4;  // 150,528 B

  // P = x @ W_in0 + b0
  gemm_skinny<<<dim3(8,16,1), blk, 0, stream>>>(x, W_in0, b0, P, PART,
      512, 32, 32, 8192, 0L, 16384L, 512L, 512L, 1, 0);
  // layer 0 recurrence
  rnn_seq<<<dim3(16), dim3(1024), rnn_lds, stream>>>(P, Wh0, h, 262144L);
  // P = h0 @ W_in_rest[:,0] + b_rest[:,0]
  gemm_skinny<<<dim3(8,16,1), blk, 0, stream>>>(h, W_inr, b_r, P, PART,
      512, 512, 24576, 8192, 1536L, 524288L, 1024L, 512L, 1, 0);
  rnn_seq<<<dim3(16), dim3(1024), rnn_lds, stream>>>(P, Wh_r, h + 512, 524288L);
  // P = h1 @ W_in_rest[:,1] + b_rest[:,1]
  gemm_skinny<<<dim3(8,16,1), blk, 0, stream>>>(h + 512, W_inr + 262144, b_r + 512, P, PART,
      512, 512, 24576, 8192, 1536L, 524288L, 1024L, 512L, 1, 0);
  rnn_seq<<<dim3(16), dim3(1024), rnn_lds, stream>>>(P, Wh_r + 262144, h + 1024, 524288L);
  // FF1: gelu(cat @ W_ff1 + b_ff1)
  gemm_skinny<<<dim3(32,16,1), blk, 0, stream>>>(h, W_ff1, b_ff1, FF, PART,
      2048, 1536, 24576, 32768, 1536L, 3145728L, 2048L, 2048L, 1, 2);
  // FF2 (split-2): ENC = FF @ W_ff2 + b_ff2
  gemm_skinny<<<dim3(8,16,2), blk, 0, stream>>>(FF, W_ff2, b_ff2, ENC, PART,
      512, 2048, 32768, 8192, 2048L, 1048576L, 512L, 512L, 2, 0);
  reduce_ep<<<dim3(4096), blk, 0, stream>>>(PART, b_ff2, ENC,
      2, 512, 8192, 512L, 512L, 0, 16*128*512, 16);
  // decoder: Z0 = tanh(ENC @ W_d0 + b_d0)   (split-8)
  gemm_skinny<<<dim3(32,1,8), blk, 0, stream>>>(ENC, W_d0, b_d0, Z0, PART,
      2048, 8192, 8192, 2048, 0L, 0L, 0L, 0L, 8, 0);
  reduce_ep<<<dim3(1024), blk, 0, stream>>>(PART, b_d0, Z0,
      8, 2048, 2048, 0L, 0L, 1, 128*2048, 1);
  // Z1 = tanh(Z0 @ W_dmid[0] + b_dmid[0])
  gemm_skinny<<<dim3(32,1,8), blk, 0, stream>>>(Z0, W_dmid, b_dmid, Z1, PART,
      2048, 2048, 2048, 2048, 0L, 0L, 0L, 0L, 8, 0);
  reduce_ep<<<dim3(1024), blk, 0, stream>>>(PART, b_dmid, Z1,
      8, 2048, 2048, 0L, 0L, 1, 128*2048, 1);
  // Z2 = tanh(Z1 @ W_dmid[1] + b_dmid[1])
  gemm_skinny<<<dim3(32,1,8), blk, 0, stream>>>(Z1, W_dmid + 4194304, b_dmid + 2048, Z2, PART,
      2048, 2048, 2048, 2048, 0L, 0L, 0L, 0L, 8, 0);
  reduce_ep<<<dim3(1024), blk, 0, stream>>>(PART, b_dmid + 2048, Z2,
      8, 2048, 2048, 0L, 0L, 1, 128*2048, 1);
  // Y = Z2 @ W_dout + b_dout -> d_out [1,128,1024]
  gemm_skinny<<<dim3(16,1,8), blk, 0, stream>>>(Z2, W_dout, b_dout, (float*)d_out, PART,
      1024, 2048, 2048, 1024, 0L, 0L, 0L, 0L, 8, 0);
  reduce_ep<<<dim3(512), blk, 0, stream>>>(PART, b_dout, (float*)d_out,
      8, 1024, 1024, 0L, 0L, 0, 128*1024, 1);
}

// Round 6
// 1478.779 us; speedup vs baseline: 1.2761x; 1.1068x over previous
//
#include <hip/hip_runtime.h>
#include <hip/hip_bf16.h>
#include <hip/hip_fp16.h>

#define E_ 16
#define T_ 128

typedef _Float16 h2_t __attribute__((ext_vector_type(2)));

__device__ __forceinline__ float fdot2u(uint32_t w, uint32_t h, float acc) {
#if __has_builtin(__builtin_amdgcn_fdot2)
  return __builtin_amdgcn_fdot2(__builtin_bit_cast(h2_t, w),
                                __builtin_bit_cast(h2_t, h), acc, false);
#else
  h2_t wv = __builtin_bit_cast(h2_t, w), hv = __builtin_bit_cast(h2_t, h);
  return acc + (float)wv.x * (float)hv.x + (float)wv.y * (float)hv.y;
#endif
}

__device__ __forceinline__ uint32_t rdlane(uint32_t v, int l) {
  return (uint32_t)__builtin_amdgcn_readlane((int)v, l);
}

__device__ __forceinline__ uint32_t packh2(float a, float b) {
  h2_t p; p.x = (_Float16)a; p.y = (_Float16)b;
  return __builtin_bit_cast(uint32_t, p);
}

__device__ __forceinline__ float apply_act(float v, int act) {
  if (act == 1) return tanhf(v);
  if (act == 2) { // jax.nn.gelu approximate=True
    const float c = 0.7978845608028654f;
    return 0.5f * v * (1.0f + tanhf(c * (v + 0.044715f * v * v * v)));
  }
  return v;
}

// ---- skinny GEMM: C[128,N] = act(A[128,K] @ W[K,N] + bias), batched over e (grid.y), split-K (grid.z) ----
__global__ void __launch_bounds__(256) gemm_skinny(
    const float* __restrict__ A, const float* __restrict__ W,
    const float* __restrict__ bias, float* __restrict__ C, float* __restrict__ part,
    int N, int K, int lda, int ldc,
    long sAe, long sWe, long sBe, long sCe,
    int S, int act)
{
  int n0 = blockIdx.x * 64;
  int e  = blockIdx.y;
  int s  = blockIdx.z;
  const float* Ae = A + (long)e * sAe;
  const float* We = W + (long)e * sWe + n0;
  int kper = K / S;
  int kb = s * kper, ke = kb + kper;

  __shared__ float As[32][132];   // A-chunk transposed: As[kk][m], pad 4
  __shared__ float Ws[32][68];    // W-chunk: Ws[kk][n], pad 4
  int tid = threadIdx.x;
  int tn = tid & 15, tm = tid >> 4;
  float acc[8][4];
  #pragma unroll
  for (int i = 0; i < 8; ++i)
    #pragma unroll
    for (int j = 0; j < 4; ++j) acc[i][j] = 0.f;

  for (int k0 = kb; k0 < ke; k0 += 32) {
    #pragma unroll
    for (int i = 0; i < 4; ++i) {
      int li = i * 1024 + tid * 4;
      int r = li >> 5, kk = li & 31;
      float4 a4 = *(const float4*)(Ae + (long)r * lda + k0 + kk);
      As[kk+0][r] = a4.x; As[kk+1][r] = a4.y; As[kk+2][r] = a4.z; As[kk+3][r] = a4.w;
    }
    #pragma unroll
    for (int i = 0; i < 2; ++i) {
      int li = i * 1024 + tid * 4;
      int kk = li >> 6, j = li & 63;
      *(float4*)&Ws[kk][j] = *(const float4*)(We + (long)(k0 + kk) * N + j);
    }
    __syncthreads();
    #pragma unroll
    for (int kk = 0; kk < 32; ++kk) {
      float4 a0 = *(const float4*)&As[kk][tm*8];
      float4 a1 = *(const float4*)&As[kk][tm*8+4];
      float4 w4 = *(const float4*)&Ws[kk][tn*4];
      float av[8] = {a0.x,a0.y,a0.z,a0.w,a1.x,a1.y,a1.z,a1.w};
      float wv[4] = {w4.x,w4.y,w4.z,w4.w};
      #pragma unroll
      for (int i2 = 0; i2 < 8; ++i2)
        #pragma unroll
        for (int j2 = 0; j2 < 4; ++j2)
          acc[i2][j2] = fmaf(av[i2], wv[j2], acc[i2][j2]);
    }
    __syncthreads();
  }

  if (S == 1) {
    #pragma unroll
    for (int i2 = 0; i2 < 8; ++i2) {
      int r = tm * 8 + i2;
      float4 o; float* op = (float*)&o;
      #pragma unroll
      for (int j2 = 0; j2 < 4; ++j2)
        op[j2] = apply_act(acc[i2][j2] + bias[(long)e*sBe + n0 + tn*4 + j2], act);
      *(float4*)(C + (long)e*sCe + (long)r*ldc + n0 + tn*4) = o;
    }
  } else {
    float* pp = part + ((long)(s * gridDim.y + e) * 128) * N;
    #pragma unroll
    for (int i2 = 0; i2 < 8; ++i2) {
      int r = tm * 8 + i2;
      float4 o; float* op = (float*)&o;
      #pragma unroll
      for (int j2 = 0; j2 < 4; ++j2) op[j2] = acc[i2][j2];
      *(float4*)(pp + (long)r * N + n0 + tn*4) = o;
    }
  }
}

// reduce split-K partials + bias + act -> C
__global__ void __launch_bounds__(256) reduce_ep(
    const float* __restrict__ part, const float* __restrict__ bias, float* __restrict__ C,
    int S, int N, int ldc, long sBe, long sCe, int act, int total, int Eb)
{
  int idx = blockIdx.x * 256 + threadIdx.x;
  if (idx >= total) return;
  int n = idx % N;
  int r = (idx / N) & 127;
  int e = idx / (N * 128);
  long sstride = (long)Eb * 128 * N;
  float v = 0.f;
  for (int s = 0; s < S; ++s) v += part[s * sstride + ((long)e * 128 + r) * N + n];
  v = apply_act(v + bias[(long)e * sBe + n], act);
  C[(long)e * sCe + (long)r * ldc + n] = v;
}

// ---- sequential RNN layer: h[t] = tanh(P[t] + h[t-1] @ Wh) ----
// ONE workgroup per encoder, block = 1024 (16 waves), 1 WG/CU.
// Layout: wave w -> K-quarter kq = w>>2 (128 k-vals = 64 pairs, wave-uniform),
// column group colg = w&3; thread owns cols c0 = colg*128 + 2*lane, c0+1.
// Weight pairs/thread = 64 kpl x 2 cols = 128 uints: 46 kpl (92 regs) in VGPR,
// 18 kpl (36 uints, 9x uint4) in LDS (147456 B).
// h broadcast: each lane loads ONE hbuf uint (pair kq*64+lane); v_readlane
// broadcasts pair L; each broadcast feeds TWO dot2 (2 cols) -> 64 rdl + 128
// dot2 per step (R5 was ~1:1). Cross-quarter reduce: kq 1..3 write float2
// partials to 6 KB LDS; kq 0 sums + tanh + writes h. 2 barriers/step.
// amdgpu_waves_per_eu(4,4): 16 waves/CU = 4/EU -> full 128-VGPR budget
// (default targeted 2 WG/CU = 64 regs and spilled ~46 pairs to scratch,
// 8 MB/dispatch of scratch writes in R5).
#define RNN_NV 46   // kpl in VGPRs (x2 cols = 92 regs)
#define RNN_NG 9    // uint4 LDS groups (18 kpl -> 36 uints/thread)

__global__ void __launch_bounds__(1024)
__attribute__((amdgpu_waves_per_eu(4, 4)))
rnn_seq(
    const float* __restrict__ P,     // [T][E][512], pre-activation incl. bias
    const float* __restrict__ Wh,    // + e*sWe : [512][512]
    float* __restrict__ H,           // (t*E+e)*1536 + col  (layer offset applied by caller)
    long sWe)
{
  extern __shared__ uint32_t smem[];
  uint32_t* lw   = smem;                       // [RNN_NG][1024][4] = 147456 B
  uint32_t* hbuf = smem + RNN_NG * 4096;       // 256 uints = 512 fp16
  float*    red  = (float*)(hbuf + 256);       // [3][512] floats = 6144 B

  int tid  = threadIdx.x;
  int lane = tid & 63;
  int wid  = tid >> 6;
  int kq   = wid >> 2;                 // K-quarter 0..3 (wave-uniform)
  int colg = wid & 3;
  int c0   = colg * 128 + lane * 2;    // this thread's two columns
  int e    = blockIdx.x;

  const float* W = Wh + (long)e * sWe;  // element (k,c) at W[k*512 + c]

  // kpl q covers k = kq*128 + 2q, 2q+1 ; w0=col c0, w1=col c0+1
  uint32_t w0[RNN_NV], w1[RNN_NV];
  #pragma unroll
  for (int q = 0; q < RNN_NV; ++q) {
    int k = kq * 128 + 2 * q;
    float2 ra = *(const float2*)(W + (long)k * 512 + c0);
    float2 rb = *(const float2*)(W + (long)(k + 1) * 512 + c0);
    w0[q] = packh2(ra.x, rb.x);
    w1[q] = packh2(ra.y, rb.y);
  }
  for (int g = 0; g < RNN_NG; ++g) {
    int k = kq * 128 + 2 * (RNN_NV + 2 * g);
    float2 ra = *(const float2*)(W + (long)(k + 0) * 512 + c0);
    float2 rb = *(const float2*)(W + (long)(k + 1) * 512 + c0);
    float2 rc = *(const float2*)(W + (long)(k + 2) * 512 + c0);
    float2 rd = *(const float2*)(W + (long)(k + 3) * 512 + c0);
    uint4 v;
    v.x = packh2(ra.x, rb.x);   // kpl RNN_NV+2g,   col c0
    v.y = packh2(ra.y, rb.y);   //                  col c0+1
    v.z = packh2(rc.x, rd.x);   // kpl RNN_NV+2g+1, col c0
    v.w = packh2(rc.y, rd.y);   //                  col c0+1
    *(uint4*)(lw + ((long)g * 1024 + tid) * 4) = v;
  }
  if (tid < 256) hbuf[tid] = 0;   // h(-1) = 0
  __syncthreads();

  for (int t = 0; t < T_; ++t) {
    uint32_t hr = hbuf[kq * 64 + lane];   // pair kq*64+lane = h[2P], h[2P+1]
    float a0 = 0.f, a1 = 0.f;
    #pragma unroll
    for (int L = 0; L < RNN_NV; ++L) {
      uint32_t hb = rdlane(hr, L);
      a0 = fdot2u(w0[L], hb, a0);
      a1 = fdot2u(w1[L], hb, a1);
    }
    #pragma unroll
    for (int g = 0; g < RNN_NG; ++g) {
      uint4 v = *(const uint4*)(lw + (g * 1024 + tid) * 4);
      uint32_t hb0 = rdlane(hr, RNN_NV + 2 * g);
      uint32_t hb1 = rdlane(hr, RNN_NV + 2 * g + 1);
      a0 = fdot2u(v.x, hb0, a0);
      a1 = fdot2u(v.y, hb0, a1);
      a0 = fdot2u(v.z, hb1, a0);
      a1 = fdot2u(v.w, hb1, a1);
    }
    if (kq) *(float2*)(red + (kq - 1) * 512 + c0) = make_float2(a0, a1);
    __syncthreads();                 // partials ready; all hbuf reads done
    if (kq == 0) {
      float2 pv = *(const float2*)(P + ((long)t * E_ + e) * 512 + c0);
      float v0 = a0 + red[c0]     + red[512 + c0]     + red[1024 + c0]     + pv.x;
      float v1 = a1 + red[c0 + 1] + red[512 + c0 + 1] + red[1024 + c0 + 1] + pv.y;
      v0 = tanhf(v0); v1 = tanhf(v1);
      *(float2*)(H + ((long)t * E_ + e) * 1536 + c0) = make_float2(v0, v1);
      hbuf[colg * 64 + lane] = packh2(v0, v1);
    }
    __syncthreads();                 // new h visible for next step
  }
}

extern "C" void kernel_launch(void* const* d_in, const int* in_sizes, int n_in,
                              void* d_out, int out_size, void* d_ws, size_t ws_size,
                              hipStream_t stream)
{
  const float* x      = (const float*)d_in[0];
  const float* W_in0  = (const float*)d_in[1];
  const float* Wh0    = (const float*)d_in[2];
  const float* b0     = (const float*)d_in[3];
  const float* W_inr  = (const float*)d_in[4];
  const float* Wh_r   = (const float*)d_in[5];
  const float* b_r    = (const float*)d_in[6];
  const float* W_ff1  = (const float*)d_in[7];
  const float* b_ff1  = (const float*)d_in[8];
  const float* W_ff2  = (const float*)d_in[9];
  const float* b_ff2  = (const float*)d_in[10];
  const float* W_d0   = (const float*)d_in[11];
  const float* b_d0   = (const float*)d_in[12];
  const float* W_dmid = (const float*)d_in[13];
  const float* b_dmid = (const float*)d_in[14];
  const float* W_dout = (const float*)d_in[15];
  const float* b_dout = (const float*)d_in[16];
  float* ws = (float*)d_ws;

  // workspace layout (floats)
  float* h    = ws;                    // [T][E][3][512]  3,145,728
  float* P    = ws + 3145728;          // [T][E][512]     1,048,576
  float* FF   = ws + 4194304;          // [T][E][2048]    4,194,304
  float* ENC  = ws + 8388608;          // [T][E*512]      1,048,576
  float* Z0   = ws + 9437184;          // [128][2048]       262,144
  float* Z1   = ws + 9699328;
  float* Z2   = ws + 9961472;
  float* PART = ws + 10223616;         // split-K partials 2,097,152

  (void)in_sizes; (void)n_in; (void)out_size; (void)ws_size;

  dim3 blk(256);
  const size_t rnn_lds = (size_t)(RNN_NG * 4096 + 256) * 4 + 3 * 512 * 4;  // 154,624 B

  // P = x @ W_in0 + b0
  gemm_skinny<<<dim3(8,16,1), blk, 0, stream>>>(x, W_in0, b0, P, PART,
      512, 32, 32, 8192, 0L, 16384L, 512L, 512L, 1, 0);
  // layer 0 recurrence
  rnn_seq<<<dim3(16), dim3(1024), rnn_lds, stream>>>(P, Wh0, h, 262144L);
  // P = h0 @ W_in_rest[:,0] + b_rest[:,0]
  gemm_skinny<<<dim3(8,16,1), blk, 0, stream>>>(h, W_inr, b_r, P, PART,
      512, 512, 24576, 8192, 1536L, 524288L, 1024L, 512L, 1, 0);
  rnn_seq<<<dim3(16), dim3(1024), rnn_lds, stream>>>(P, Wh_r, h + 512, 524288L);
  // P = h1 @ W_in_rest[:,1] + b_rest[:,1]
  gemm_skinny<<<dim3(8,16,1), blk, 0, stream>>>(h + 512, W_inr + 262144, b_r + 512, P, PART,
      512, 512, 24576, 8192, 1536L, 524288L, 1024L, 512L, 1, 0);
  rnn_seq<<<dim3(16), dim3(1024), rnn_lds, stream>>>(P, Wh_r + 262144, h + 1024, 524288L);
  // FF1: gelu(cat @ W_ff1 + b_ff1)
  gemm_skinny<<<dim3(32,16,1), blk, 0, stream>>>(h, W_ff1, b_ff1, FF, PART,
      2048, 1536, 24576, 32768, 1536L, 3145728L, 2048L, 2048L, 1, 2);
  // FF2 (split-2): ENC = FF @ W_ff2 + b_ff2
  gemm_skinny<<<dim3(8,16,2), blk, 0, stream>>>(FF, W_ff2, b_ff2, ENC, PART,
      512, 2048, 32768, 8192, 2048L, 1048576L, 512L, 512L, 2, 0);
  reduce_ep<<<dim3(4096), blk, 0, stream>>>(PART, b_ff2, ENC,
      2, 512, 8192, 512L, 512L, 0, 16*128*512, 16);
  // decoder: Z0 = tanh(ENC @ W_d0 + b_d0)   (split-8)
  gemm_skinny<<<dim3(32,1,8), blk, 0, stream>>>(ENC, W_d0, b_d0, Z0, PART,
      2048, 8192, 8192, 2048, 0L, 0L, 0L, 0L, 8, 0);
  reduce_ep<<<dim3(1024), blk, 0, stream>>>(PART, b_d0, Z0,
      8, 2048, 2048, 0L, 0L, 1, 128*2048, 1);
  // Z1 = tanh(Z0 @ W_dmid[0] + b_dmid[0])
  gemm_skinny<<<dim3(32,1,8), blk, 0, stream>>>(Z0, W_dmid, b_dmid, Z1, PART,
      2048, 2048, 2048, 2048, 0L, 0L, 0L, 0L, 8, 0);
  reduce_ep<<<dim3(1024), blk, 0, stream>>>(PART, b_dmid, Z1,
      8, 2048, 2048, 0L, 0L, 1, 128*2048, 1);
  // Z2 = tanh(Z1 @ W_dmid[1] + b_dmid[1])
  gemm_skinny<<<dim3(32,1,8), blk, 0, stream>>>(Z1, W_dmid + 4194304, b_dmid + 2048, Z2, PART,
      2048, 2048, 2048, 2048, 0L, 0L, 0L, 0L, 8, 0);
  reduce_ep<<<dim3(1024), blk, 0, stream>>>(PART, b_dmid + 2048, Z2,
      8, 2048, 2048, 0L, 0L, 1, 128*2048, 1);
  // Y = Z2 @ W_dout + b_dout -> d_out [1,128,1024]
  gemm_skinny<<<dim3(16,1,8), blk, 0, stream>>>(Z2, W_dout, b_dout, (float*)d_out, PART,
      1024, 2048, 2048, 1024, 0L, 0L, 0L, 0L, 8, 0);
  reduce_ep<<<dim3(512), blk, 0, stream>>>(PART, b_dout, (float*)d_out,
      8, 1024, 1024, 0L, 0L, 0, 128*1024, 1);
}

// Round 7
// 1403.381 us; speedup vs baseline: 1.3446x; 1.0537x over previous
//
#include <hip/hip_runtime.h>
#include <hip/hip_bf16.h>
#include <hip/hip_fp16.h>

#define E_ 16
#define T_ 128

typedef _Float16 h2_t __attribute__((ext_vector_type(2)));

__device__ __forceinline__ float fdot2u(uint32_t w, uint32_t h, float acc) {
#if __has_builtin(__builtin_amdgcn_fdot2)
  return __builtin_amdgcn_fdot2(__builtin_bit_cast(h2_t, w),
                                __builtin_bit_cast(h2_t, h), acc, false);
#else
  h2_t wv = __builtin_bit_cast(h2_t, w), hv = __builtin_bit_cast(h2_t, h);
  return acc + (float)wv.x * (float)hv.x + (float)wv.y * (float)hv.y;
#endif
}

__device__ __forceinline__ uint32_t rdlane(uint32_t v, int l) {
  return (uint32_t)__builtin_amdgcn_readlane((int)v, l);
}

__device__ __forceinline__ uint32_t packh2(float a, float b) {
  h2_t p; p.x = (_Float16)a; p.y = (_Float16)b;
  return __builtin_bit_cast(uint32_t, p);
}

__device__ __forceinline__ float apply_act(float v, int act) {
  if (act == 1) return tanhf(v);
  if (act == 2) { // jax.nn.gelu approximate=True
    const float c = 0.7978845608028654f;
    return 0.5f * v * (1.0f + tanhf(c * (v + 0.044715f * v * v * v)));
  }
  return v;
}

// ---- skinny GEMM: C[128,N] = act(A[128,K] @ W[K,N] + bias), batched over e (grid.y), split-K (grid.z) ----
__global__ void __launch_bounds__(256) gemm_skinny(
    const float* __restrict__ A, const float* __restrict__ W,
    const float* __restrict__ bias, float* __restrict__ C, float* __restrict__ part,
    int N, int K, int lda, int ldc,
    long sAe, long sWe, long sBe, long sCe,
    int S, int act)
{
  int n0 = blockIdx.x * 64;
  int e  = blockIdx.y;
  int s  = blockIdx.z;
  const float* Ae = A + (long)e * sAe;
  const float* We = W + (long)e * sWe + n0;
  int kper = K / S;
  int kb = s * kper, ke = kb + kper;

  __shared__ float As[32][132];   // A-chunk transposed: As[kk][m], pad 4
  __shared__ float Ws[32][68];    // W-chunk: Ws[kk][n], pad 4
  int tid = threadIdx.x;
  int tn = tid & 15, tm = tid >> 4;
  float acc[8][4];
  #pragma unroll
  for (int i = 0; i < 8; ++i)
    #pragma unroll
    for (int j = 0; j < 4; ++j) acc[i][j] = 0.f;

  for (int k0 = kb; k0 < ke; k0 += 32) {
    #pragma unroll
    for (int i = 0; i < 4; ++i) {
      int li = i * 1024 + tid * 4;
      int r = li >> 5, kk = li & 31;
      float4 a4 = *(const float4*)(Ae + (long)r * lda + k0 + kk);
      As[kk+0][r] = a4.x; As[kk+1][r] = a4.y; As[kk+2][r] = a4.z; As[kk+3][r] = a4.w;
    }
    #pragma unroll
    for (int i = 0; i < 2; ++i) {
      int li = i * 1024 + tid * 4;
      int kk = li >> 6, j = li & 63;
      *(float4*)&Ws[kk][j] = *(const float4*)(We + (long)(k0 + kk) * N + j);
    }
    __syncthreads();
    #pragma unroll
    for (int kk = 0; kk < 32; ++kk) {
      float4 a0 = *(const float4*)&As[kk][tm*8];
      float4 a1 = *(const float4*)&As[kk][tm*8+4];
      float4 w4 = *(const float4*)&Ws[kk][tn*4];
      float av[8] = {a0.x,a0.y,a0.z,a0.w,a1.x,a1.y,a1.z,a1.w};
      float wv[4] = {w4.x,w4.y,w4.z,w4.w};
      #pragma unroll
      for (int i2 = 0; i2 < 8; ++i2)
        #pragma unroll
        for (int j2 = 0; j2 < 4; ++j2)
          acc[i2][j2] = fmaf(av[i2], wv[j2], acc[i2][j2]);
    }
    __syncthreads();
  }

  if (S == 1) {
    #pragma unroll
    for (int i2 = 0; i2 < 8; ++i2) {
      int r = tm * 8 + i2;
      float4 o; float* op = (float*)&o;
      #pragma unroll
      for (int j2 = 0; j2 < 4; ++j2)
        op[j2] = apply_act(acc[i2][j2] + bias[(long)e*sBe + n0 + tn*4 + j2], act);
      *(float4*)(C + (long)e*sCe + (long)r*ldc + n0 + tn*4) = o;
    }
  } else {
    float* pp = part + ((long)(s * gridDim.y + e) * 128) * N;
    #pragma unroll
    for (int i2 = 0; i2 < 8; ++i2) {
      int r = tm * 8 + i2;
      float4 o; float* op = (float*)&o;
      #pragma unroll
      for (int j2 = 0; j2 < 4; ++j2) op[j2] = acc[i2][j2];
      *(float4*)(pp + (long)r * N + n0 + tn*4) = o;
    }
  }
}

// reduce split-K partials + bias + act -> C
__global__ void __launch_bounds__(256) reduce_ep(
    const float* __restrict__ part, const float* __restrict__ bias, float* __restrict__ C,
    int S, int N, int ldc, long sBe, long sCe, int act, int total, int Eb)
{
  int idx = blockIdx.x * 256 + threadIdx.x;
  if (idx >= total) return;
  int n = idx % N;
  int r = (idx / N) & 127;
  int e = idx / (N * 128);
  long sstride = (long)Eb * 128 * N;
  float v = 0.f;
  for (int s = 0; s < S; ++s) v += part[s * sstride + ((long)e * 128 + r) * N + n];
  v = apply_act(v + bias[(long)e * sBe + n], act);
  C[(long)e * sCe + (long)r * ldc + n] = v;
}

// ---- sequential RNN layer: h[t] = tanh(P[t] + h[t-1] @ Wh) ----
// ONE workgroup per encoder, block = 1024 (16 waves), 1 WG/CU.
// Wave w: K-quarter kq = w>>2 (wave-uniform), column group colg = w&3;
// thread owns cols c0 = colg*128 + 2*lane, c0+1.
// Weight pairs/thread = 64 kpl x 2 cols = 128 uints: 46 kpl (92 regs) VGPR,
// 18 kpl (36 uints) LDS (147456 B). Storage audit at 128 regs/thread:
// 92 regs x 1024 thr = 368 KB regs + 147 KB LDS = whole fp16 matrix resident.
// CRITICAL: use amdgpu_flat_work_group_size + amdgpu_waves_per_eu, NOT
// __launch_bounds__ — hipcc's __launch_bounds__ emits its own waves-per-eu
// that OVERRIDES amdgpu_waves_per_eu (R4/R6: VGPR capped at 64, ~46 pairs
// spilled to scratch, 5-8 MB/dispatch scratch writes). R3 (flat_wgs +
// waves_per_eu, no launch_bounds) is the only config where the 128-reg
// budget was honored.
// P(t) global load issued at loop-top (kq==0) so its ~300-500 cyc L2 latency
// hides under the dot-product phase instead of sitting after the barrier.
#define RNN_NV 46   // kpl in VGPRs (x2 cols = 92 regs)
#define RNN_NG 9    // uint4 LDS groups (18 kpl -> 36 uints/thread)

__global__ void
__attribute__((amdgpu_flat_work_group_size(1024, 1024)))
__attribute__((amdgpu_waves_per_eu(4, 4)))
rnn_seq(
    const float* __restrict__ P,     // [T][E][512], pre-activation incl. bias
    const float* __restrict__ Wh,    // + e*sWe : [512][512]
    float* __restrict__ H,           // (t*E+e)*1536 + col  (layer offset applied by caller)
    long sWe)
{
  extern __shared__ uint32_t smem[];
  uint32_t* lw   = smem;                       // [RNN_NG][1024][4] = 147456 B
  uint32_t* hbuf = smem + RNN_NG * 4096;       // 256 uints = 512 fp16
  float*    red  = (float*)(hbuf + 256);       // [3][512] floats = 6144 B

  int tid  = threadIdx.x;
  int lane = tid & 63;
  int wid  = tid >> 6;
  int kq   = wid >> 2;                 // K-quarter 0..3 (wave-uniform)
  int colg = wid & 3;
  int c0   = colg * 128 + lane * 2;    // this thread's two columns
  int e    = blockIdx.x;

  const float* W = Wh + (long)e * sWe;  // element (k,c) at W[k*512 + c]

  // kpl q covers k = kq*128 + 2q, 2q+1 ; w0=col c0, w1=col c0+1
  uint32_t w0[RNN_NV], w1[RNN_NV];
  #pragma unroll
  for (int q = 0; q < RNN_NV; ++q) {
    int k = kq * 128 + 2 * q;
    float2 ra = *(const float2*)(W + (long)k * 512 + c0);
    float2 rb = *(const float2*)(W + (long)(k + 1) * 512 + c0);
    w0[q] = packh2(ra.x, rb.x);
    w1[q] = packh2(ra.y, rb.y);
  }
  for (int g = 0; g < RNN_NG; ++g) {
    int k = kq * 128 + 2 * (RNN_NV + 2 * g);
    float2 ra = *(const float2*)(W + (long)(k + 0) * 512 + c0);
    float2 rb = *(const float2*)(W + (long)(k + 1) * 512 + c0);
    float2 rc = *(const float2*)(W + (long)(k + 2) * 512 + c0);
    float2 rd = *(const float2*)(W + (long)(k + 3) * 512 + c0);
    uint4 v;
    v.x = packh2(ra.x, rb.x);   // kpl RNN_NV+2g,   col c0
    v.y = packh2(ra.y, rb.y);   //                  col c0+1
    v.z = packh2(rc.x, rd.x);   // kpl RNN_NV+2g+1, col c0
    v.w = packh2(rc.y, rd.y);   //                  col c0+1
    *(uint4*)(lw + ((long)g * 1024 + tid) * 4) = v;
  }
  if (tid < 256) hbuf[tid] = 0;   // h(-1) = 0
  __syncthreads();

  for (int t = 0; t < T_; ++t) {
    // issue P load early (kq==0 only) — latency hides under the dot phase
    float2 pv = make_float2(0.f, 0.f);
    if (kq == 0) pv = *(const float2*)(P + ((long)t * E_ + e) * 512 + c0);
    uint32_t hr = hbuf[kq * 64 + lane];   // pair kq*64+lane = h[2P], h[2P+1]
    float a0 = 0.f, a1 = 0.f;
    #pragma unroll
    for (int L = 0; L < RNN_NV; ++L) {
      uint32_t hb = rdlane(hr, L);
      a0 = fdot2u(w0[L], hb, a0);
      a1 = fdot2u(w1[L], hb, a1);
    }
    #pragma unroll
    for (int g = 0; g < RNN_NG; ++g) {
      uint4 v = *(const uint4*)(lw + (g * 1024 + tid) * 4);
      uint32_t hb0 = rdlane(hr, RNN_NV + 2 * g);
      uint32_t hb1 = rdlane(hr, RNN_NV + 2 * g + 1);
      a0 = fdot2u(v.x, hb0, a0);
      a1 = fdot2u(v.y, hb0, a1);
      a0 = fdot2u(v.z, hb1, a0);
      a1 = fdot2u(v.w, hb1, a1);
    }
    if (kq) *(float2*)(red + (kq - 1) * 512 + c0) = make_float2(a0, a1);
    __syncthreads();                 // partials ready; all hbuf reads done
    if (kq == 0) {
      float v0 = a0 + red[c0]     + red[512 + c0]     + red[1024 + c0]     + pv.x;
      float v1 = a1 + red[c0 + 1] + red[512 + c0 + 1] + red[1024 + c0 + 1] + pv.y;
      v0 = tanhf(v0); v1 = tanhf(v1);
      *(float2*)(H + ((long)t * E_ + e) * 1536 + c0) = make_float2(v0, v1);
      hbuf[colg * 64 + lane] = packh2(v0, v1);
    }
    __syncthreads();                 // new h visible for next step
  }
}

extern "C" void kernel_launch(void* const* d_in, const int* in_sizes, int n_in,
                              void* d_out, int out_size, void* d_ws, size_t ws_size,
                              hipStream_t stream)
{
  const float* x      = (const float*)d_in[0];
  const float* W_in0  = (const float*)d_in[1];
  const float* Wh0    = (const float*)d_in[2];
  const float* b0     = (const float*)d_in[3];
  const float* W_inr  = (const float*)d_in[4];
  const float* Wh_r   = (const float*)d_in[5];
  const float* b_r    = (const float*)d_in[6];
  const float* W_ff1  = (const float*)d_in[7];
  const float* b_ff1  = (const float*)d_in[8];
  const float* W_ff2  = (const float*)d_in[9];
  const float* b_ff2  = (const float*)d_in[10];
  const float* W_d0   = (const float*)d_in[11];
  const float* b_d0   = (const float*)d_in[12];
  const float* W_dmid = (const float*)d_in[13];
  const float* b_dmid = (const float*)d_in[14];
  const float* W_dout = (const float*)d_in[15];
  const float* b_dout = (const float*)d_in[16];
  float* ws = (float*)d_ws;

  // workspace layout (floats)
  float* h    = ws;                    // [T][E][3][512]  3,145,728
  float* P    = ws + 3145728;          // [T][E][512]     1,048,576
  float* FF   = ws + 4194304;          // [T][E][2048]    4,194,304
  float* ENC  = ws + 8388608;          // [T][E*512]      1,048,576
  float* Z0   = ws + 9437184;          // [128][2048]       262,144
  float* Z1   = ws + 9699328;
  float* Z2   = ws + 9961472;
  float* PART = ws + 10223616;         // split-K partials 2,097,152

  (void)in_sizes; (void)n_in; (void)out_size; (void)ws_size;

  dim3 blk(256);
  const size_t rnn_lds = (size_t)(RNN_NG * 4096 + 256) * 4 + 3 * 512 * 4;  // 154,624 B

  // P = x @ W_in0 + b0
  gemm_skinny<<<dim3(8,16,1), blk, 0, stream>>>(x, W_in0, b0, P, PART,
      512, 32, 32, 8192, 0L, 16384L, 512L, 512L, 1, 0);
  // layer 0 recurrence
  rnn_seq<<<dim3(16), dim3(1024), rnn_lds, stream>>>(P, Wh0, h, 262144L);
  // P = h0 @ W_in_rest[:,0] + b_rest[:,0]
  gemm_skinny<<<dim3(8,16,1), blk, 0, stream>>>(h, W_inr, b_r, P, PART,
      512, 512, 24576, 8192, 1536L, 524288L, 1024L, 512L, 1, 0);
  rnn_seq<<<dim3(16), dim3(1024), rnn_lds, stream>>>(P, Wh_r, h + 512, 524288L);
  // P = h1 @ W_in_rest[:,1] + b_rest[:,1]
  gemm_skinny<<<dim3(8,16,1), blk, 0, stream>>>(h + 512, W_inr + 262144, b_r + 512, P, PART,
      512, 512, 24576, 8192, 1536L, 524288L, 1024L, 512L, 1, 0);
  rnn_seq<<<dim3(16), dim3(1024), rnn_lds, stream>>>(P, Wh_r + 262144, h + 1024, 524288L);
  // FF1: gelu(cat @ W_ff1 + b_ff1)
  gemm_skinny<<<dim3(32,16,1), blk, 0, stream>>>(h, W_ff1, b_ff1, FF, PART,
      2048, 1536, 24576, 32768, 1536L, 3145728L, 2048L, 2048L, 1, 2);
  // FF2 (split-2): ENC = FF @ W_ff2 + b_ff2
  gemm_skinny<<<dim3(8,16,2), blk, 0, stream>>>(FF, W_ff2, b_ff2, ENC, PART,
      512, 2048, 32768, 8192, 2048L, 1048576L, 512L, 512L, 2, 0);
  reduce_ep<<<dim3(4096), blk, 0, stream>>>(PART, b_ff2, ENC,
      2, 512, 8192, 512L, 512L, 0, 16*128*512, 16);
  // decoder: Z0 = tanh(ENC @ W_d0 + b_d0)   (split-8)
  gemm_skinny<<<dim3(32,1,8), blk, 0, stream>>>(ENC, W_d0, b_d0, Z0, PART,
      2048, 8192, 8192, 2048, 0L, 0L, 0L, 0L, 8, 0);
  reduce_ep<<<dim3(1024), blk, 0, stream>>>(PART, b_d0, Z0,
      8, 2048, 2048, 0L, 0L, 1, 128*2048, 1);
  // Z1 = tanh(Z0 @ W_dmid[0] + b_dmid[0])
  gemm_skinny<<<dim3(32,1,8), blk, 0, stream>>>(Z0, W_dmid, b_dmid, Z1, PART,
      2048, 2048, 2048, 2048, 0L, 0L, 0L, 0L, 8, 0);
  reduce_ep<<<dim3(1024), blk, 0, stream>>>(PART, b_dmid, Z1,
      8, 2048, 2048, 0L, 0L, 1, 128*2048, 1);
  // Z2 = tanh(Z1 @ W_dmid[1] + b_dmid[1])
  gemm_skinny<<<dim3(32,1,8), blk, 0, stream>>>(Z1, W_dmid + 4194304, b_dmid + 2048, Z2, PART,
      2048, 2048, 2048, 2048, 0L, 0L, 0L, 0L, 8, 0);
  reduce_ep<<<dim3(1024), blk, 0, stream>>>(PART, b_dmid + 2048, Z2,
      8, 2048, 2048, 0L, 0L, 1, 128*2048, 1);
  // Y = Z2 @ W_dout + b_dout -> d_out [1,128,1024]
  gemm_skinny<<<dim3(16,1,8), blk, 0, stream>>>(Z2, W_dout, b_dout, (float*)d_out, PART,
      1024, 2048, 2048, 1024, 0L, 0L, 0L, 0L, 8, 0);
  reduce_ep<<<dim3(512), blk, 0, stream>>>(PART, b_dout, (float*)d_out,
      8, 1024, 1024, 0L, 0L, 0, 128*1024, 1);
}

// Round 8
// 1399.651 us; speedup vs baseline: 1.3482x; 1.0027x over previous
//
#include <hip/hip_runtime.h>
#include <hip/hip_bf16.h>
#include <hip/hip_fp16.h>

#define E_ 16
#define T_ 128

typedef _Float16 h2_t __attribute__((ext_vector_type(2)));

__device__ __forceinline__ float fdot2u(uint32_t w, uint32_t h, float acc) {
#if __has_builtin(__builtin_amdgcn_fdot2)
  return __builtin_amdgcn_fdot2(__builtin_bit_cast(h2_t, w),
                                __builtin_bit_cast(h2_t, h), acc, false);
#else
  h2_t wv = __builtin_bit_cast(h2_t, w), hv = __builtin_bit_cast(h2_t, h);
  return acc + (float)wv.x * (float)hv.x + (float)wv.y * (float)hv.y;
#endif
}

__device__ __forceinline__ uint32_t rdlane(uint32_t v, int l) {
  return (uint32_t)__builtin_amdgcn_readlane((int)v, l);
}

__device__ __forceinline__ uint32_t packh2(float a, float b) {
  h2_t p; p.x = (_Float16)a; p.y = (_Float16)b;
  return __builtin_bit_cast(uint32_t, p);
}

__device__ __forceinline__ float apply_act(float v, int act) {
  if (act == 1) return tanhf(v);
  if (act == 2) { // jax.nn.gelu approximate=True
    const float c = 0.7978845608028654f;
    return 0.5f * v * (1.0f + tanhf(c * (v + 0.044715f * v * v * v)));
  }
  return v;
}

// ---- skinny GEMM: C[128,N] = act(A[128,K] @ W[K,N] + bias), batched over e (grid.y), split-K (grid.z) ----
__global__ void __launch_bounds__(256) gemm_skinny(
    const float* __restrict__ A, const float* __restrict__ W,
    const float* __restrict__ bias, float* __restrict__ C, float* __restrict__ part,
    int N, int K, int lda, int ldc,
    long sAe, long sWe, long sBe, long sCe,
    int S, int act)
{
  int n0 = blockIdx.x * 64;
  int e  = blockIdx.y;
  int s  = blockIdx.z;
  const float* Ae = A + (long)e * sAe;
  const float* We = W + (long)e * sWe + n0;
  int kper = K / S;
  int kb = s * kper, ke = kb + kper;

  __shared__ float As[32][132];   // A-chunk transposed: As[kk][m], pad 4
  __shared__ float Ws[32][68];    // W-chunk: Ws[kk][n], pad 4
  int tid = threadIdx.x;
  int tn = tid & 15, tm = tid >> 4;
  float acc[8][4];
  #pragma unroll
  for (int i = 0; i < 8; ++i)
    #pragma unroll
    for (int j = 0; j < 4; ++j) acc[i][j] = 0.f;

  for (int k0 = kb; k0 < ke; k0 += 32) {
    #pragma unroll
    for (int i = 0; i < 4; ++i) {
      int li = i * 1024 + tid * 4;
      int r = li >> 5, kk = li & 31;
      float4 a4 = *(const float4*)(Ae + (long)r * lda + k0 + kk);
      As[kk+0][r] = a4.x; As[kk+1][r] = a4.y; As[kk+2][r] = a4.z; As[kk+3][r] = a4.w;
    }
    #pragma unroll
    for (int i = 0; i < 2; ++i) {
      int li = i * 1024 + tid * 4;
      int kk = li >> 6, j = li & 63;
      *(float4*)&Ws[kk][j] = *(const float4*)(We + (long)(k0 + kk) * N + j);
    }
    __syncthreads();
    #pragma unroll
    for (int kk = 0; kk < 32; ++kk) {
      float4 a0 = *(const float4*)&As[kk][tm*8];
      float4 a1 = *(const float4*)&As[kk][tm*8+4];
      float4 w4 = *(const float4*)&Ws[kk][tn*4];
      float av[8] = {a0.x,a0.y,a0.z,a0.w,a1.x,a1.y,a1.z,a1.w};
      float wv[4] = {w4.x,w4.y,w4.z,w4.w};
      #pragma unroll
      for (int i2 = 0; i2 < 8; ++i2)
        #pragma unroll
        for (int j2 = 0; j2 < 4; ++j2)
          acc[i2][j2] = fmaf(av[i2], wv[j2], acc[i2][j2]);
    }
    __syncthreads();
  }

  if (S == 1) {
    #pragma unroll
    for (int i2 = 0; i2 < 8; ++i2) {
      int r = tm * 8 + i2;
      float4 o; float* op = (float*)&o;
      #pragma unroll
      for (int j2 = 0; j2 < 4; ++j2)
        op[j2] = apply_act(acc[i2][j2] + bias[(long)e*sBe + n0 + tn*4 + j2], act);
      *(float4*)(C + (long)e*sCe + (long)r*ldc + n0 + tn*4) = o;
    }
  } else {
    float* pp = part + ((long)(s * gridDim.y + e) * 128) * N;
    #pragma unroll
    for (int i2 = 0; i2 < 8; ++i2) {
      int r = tm * 8 + i2;
      float4 o; float* op = (float*)&o;
      #pragma unroll
      for (int j2 = 0; j2 < 4; ++j2) op[j2] = acc[i2][j2];
      *(float4*)(pp + (long)r * N + n0 + tn*4) = o;
    }
  }
}

// reduce split-K partials + bias + act -> C
__global__ void __launch_bounds__(256) reduce_ep(
    const float* __restrict__ part, const float* __restrict__ bias, float* __restrict__ C,
    int S, int N, int ldc, long sBe, long sCe, int act, int total, int Eb)
{
  int idx = blockIdx.x * 256 + threadIdx.x;
  if (idx >= total) return;
  int n = idx % N;
  int r = (idx / N) & 127;
  int e = idx / (N * 128);
  long sstride = (long)Eb * 128 * N;
  float v = 0.f;
  for (int s = 0; s < S; ++s) v += part[s * sstride + ((long)e * 128 + r) * N + n];
  v = apply_act(v + bias[(long)e * sBe + n], act);
  C[(long)e * sCe + (long)r * ldc + n] = v;
}

// ---- sequential RNN layer: h[t] = tanh(P[t] + h[t-1] @ Wh) ----
// ONE workgroup per encoder, block = 1024 (16 waves), 1 WG/CU.
// Wave w: K-quarter kq = w>>2 (wave-uniform), column group colg = w&3;
// thread owns cols c0 = colg*128 + 2*lane, c0+1.
// Weight pairs/thread = 64 kpl x 2 cols = 128 uints: 46 kpl (92 regs) VGPR,
// 18 kpl (36 uints) LDS (147456 B).
// LDS MUST BE STATIC __shared__: with extern __shared__ (R2-R7) the compiler
// assumes LDS=0 for its occupancy heuristic, targets 2 WGs/CU = 8 waves/SIMD,
// caps VGPRs at 64, and spills ~52 weight uints/thread to scratch (observed:
// VGPR_Count=64, +5 MB WRITE_SIZE, ~213 KB/CU/step L2 re-reads dominating the
// step at 2.3 us). Static 154,624 B LDS makes 1 WG/CU visible at compile time
// -> 4 waves/SIMD -> honest 128-VGPR budget; 92 weights + ~30 temps fit.
// h broadcast: one ds_read_b32/thread + v_readlane (SGPR operand of
// v_dot2_f32_f16); each broadcast pair feeds 2 dot2 (2 cols).
// Cross-quarter reduce: kq 1..3 write float2 partials to LDS; kq 0 sums +
// tanh + writes h. 2 barriers/step.
#define RNN_NV 46   // kpl in VGPRs (x2 cols = 92 regs)
#define RNN_NG 9    // uint4 LDS groups (18 kpl -> 36 uints/thread)

__global__ void
__attribute__((amdgpu_flat_work_group_size(1024, 1024)))
__attribute__((amdgpu_waves_per_eu(4, 4)))
rnn_seq(
    const float* __restrict__ P,     // [T][E][512], pre-activation incl. bias
    const float* __restrict__ Wh,    // + e*sWe : [512][512]
    float* __restrict__ H,           // (t*E+e)*1536 + col  (layer offset applied by caller)
    long sWe)
{
  __shared__ uint32_t lw[RNN_NG * 4096];   // 147,456 B
  __shared__ uint32_t hbuf[256];           //   1,024 B (512 fp16)
  __shared__ float    red[3 * 512];        //   6,144 B

  int tid  = threadIdx.x;
  int lane = tid & 63;
  int wid  = tid >> 6;
  int kq   = wid >> 2;                 // K-quarter 0..3 (wave-uniform)
  int colg = wid & 3;
  int c0   = colg * 128 + lane * 2;    // this thread's two columns
  int e    = blockIdx.x;

  const float* W = Wh + (long)e * sWe;  // element (k,c) at W[k*512 + c]

  // kpl q covers k = kq*128 + 2q, 2q+1 ; w0=col c0, w1=col c0+1
  uint32_t w0[RNN_NV], w1[RNN_NV];
  #pragma unroll
  for (int q = 0; q < RNN_NV; ++q) {
    int k = kq * 128 + 2 * q;
    float2 ra = *(const float2*)(W + (long)k * 512 + c0);
    float2 rb = *(const float2*)(W + (long)(k + 1) * 512 + c0);
    w0[q] = packh2(ra.x, rb.x);
    w1[q] = packh2(ra.y, rb.y);
  }
  for (int g = 0; g < RNN_NG; ++g) {
    int k = kq * 128 + 2 * (RNN_NV + 2 * g);
    float2 ra = *(const float2*)(W + (long)(k + 0) * 512 + c0);
    float2 rb = *(const float2*)(W + (long)(k + 1) * 512 + c0);
    float2 rc = *(const float2*)(W + (long)(k + 2) * 512 + c0);
    float2 rd = *(const float2*)(W + (long)(k + 3) * 512 + c0);
    uint4 v;
    v.x = packh2(ra.x, rb.x);   // kpl RNN_NV+2g,   col c0
    v.y = packh2(ra.y, rb.y);   //                  col c0+1
    v.z = packh2(rc.x, rd.x);   // kpl RNN_NV+2g+1, col c0
    v.w = packh2(rc.y, rd.y);   //                  col c0+1
    *(uint4*)(lw + ((long)g * 1024 + tid) * 4) = v;
  }
  if (tid < 256) hbuf[tid] = 0;   // h(-1) = 0
  __syncthreads();

  for (int t = 0; t < T_; ++t) {
    // issue P load early (kq==0 only) — latency hides under the dot phase
    float2 pv = make_float2(0.f, 0.f);
    if (kq == 0) pv = *(const float2*)(P + ((long)t * E_ + e) * 512 + c0);
    uint32_t hr = hbuf[kq * 64 + lane];   // pair kq*64+lane = h[2P], h[2P+1]
    float a0 = 0.f, a1 = 0.f;
    #pragma unroll
    for (int L = 0; L < RNN_NV; ++L) {
      uint32_t hb = rdlane(hr, L);
      a0 = fdot2u(w0[L], hb, a0);
      a1 = fdot2u(w1[L], hb, a1);
    }
    #pragma unroll
    for (int g = 0; g < RNN_NG; ++g) {
      uint4 v = *(const uint4*)(lw + (g * 1024 + tid) * 4);
      uint32_t hb0 = rdlane(hr, RNN_NV + 2 * g);
      uint32_t hb1 = rdlane(hr, RNN_NV + 2 * g + 1);
      a0 = fdot2u(v.x, hb0, a0);
      a1 = fdot2u(v.y, hb0, a1);
      a0 = fdot2u(v.z, hb1, a0);
      a1 = fdot2u(v.w, hb1, a1);
    }
    if (kq) *(float2*)(red + (kq - 1) * 512 + c0) = make_float2(a0, a1);
    __syncthreads();                 // partials ready; all hbuf reads done
    if (kq == 0) {
      float v0 = a0 + red[c0]     + red[512 + c0]     + red[1024 + c0]     + pv.x;
      float v1 = a1 + red[c0 + 1] + red[512 + c0 + 1] + red[1024 + c0 + 1] + pv.y;
      v0 = tanhf(v0); v1 = tanhf(v1);
      *(float2*)(H + ((long)t * E_ + e) * 1536 + c0) = make_float2(v0, v1);
      hbuf[colg * 64 + lane] = packh2(v0, v1);
    }
    __syncthreads();                 // new h visible for next step
  }
}

extern "C" void kernel_launch(void* const* d_in, const int* in_sizes, int n_in,
                              void* d_out, int out_size, void* d_ws, size_t ws_size,
                              hipStream_t stream)
{
  const float* x      = (const float*)d_in[0];
  const float* W_in0  = (const float*)d_in[1];
  const float* Wh0    = (const float*)d_in[2];
  const float* b0     = (const float*)d_in[3];
  const float* W_inr  = (const float*)d_in[4];
  const float* Wh_r   = (const float*)d_in[5];
  const float* b_r    = (const float*)d_in[6];
  const float* W_ff1  = (const float*)d_in[7];
  const float* b_ff1  = (const float*)d_in[8];
  const float* W_ff2  = (const float*)d_in[9];
  const float* b_ff2  = (const float*)d_in[10];
  const float* W_d0   = (const float*)d_in[11];
  const float* b_d0   = (const float*)d_in[12];
  const float* W_dmid = (const float*)d_in[13];
  const float* b_dmid = (const float*)d_in[14];
  const float* W_dout = (const float*)d_in[15];
  const float* b_dout = (const float*)d_in[16];
  float* ws = (float*)d_ws;

  // workspace layout (floats)
  float* h    = ws;                    // [T][E][3][512]  3,145,728
  float* P    = ws + 3145728;          // [T][E][512]     1,048,576
  float* FF   = ws + 4194304;          // [T][E][2048]    4,194,304
  float* ENC  = ws + 8388608;          // [T][E*512]      1,048,576
  float* Z0   = ws + 9437184;          // [128][2048]       262,144
  float* Z1   = ws + 9699328;
  float* Z2   = ws + 9961472;
  float* PART = ws + 10223616;         // split-K partials 2,097,152

  (void)in_sizes; (void)n_in; (void)out_size; (void)ws_size;

  dim3 blk(256);

  // P = x @ W_in0 + b0
  gemm_skinny<<<dim3(8,16,1), blk, 0, stream>>>(x, W_in0, b0, P, PART,
      512, 32, 32, 8192, 0L, 16384L, 512L, 512L, 1, 0);
  // layer 0 recurrence
  rnn_seq<<<dim3(16), dim3(1024), 0, stream>>>(P, Wh0, h, 262144L);
  // P = h0 @ W_in_rest[:,0] + b_rest[:,0]
  gemm_skinny<<<dim3(8,16,1), blk, 0, stream>>>(h, W_inr, b_r, P, PART,
      512, 512, 24576, 8192, 1536L, 524288L, 1024L, 512L, 1, 0);
  rnn_seq<<<dim3(16), dim3(1024), 0, stream>>>(P, Wh_r, h + 512, 524288L);
  // P = h1 @ W_in_rest[:,1] + b_rest[:,1]
  gemm_skinny<<<dim3(8,16,1), blk, 0, stream>>>(h + 512, W_inr + 262144, b_r + 512, P, PART,
      512, 512, 24576, 8192, 1536L, 524288L, 1024L, 512L, 1, 0);
  rnn_seq<<<dim3(16), dim3(1024), 0, stream>>>(P, Wh_r + 262144, h + 1024, 524288L);
  // FF1: gelu(cat @ W_ff1 + b_ff1)
  gemm_skinny<<<dim3(32,16,1), blk, 0, stream>>>(h, W_ff1, b_ff1, FF, PART,
      2048, 1536, 24576, 32768, 1536L, 3145728L, 2048L, 2048L, 1, 2);
  // FF2 (split-2): ENC = FF @ W_ff2 + b_ff2
  gemm_skinny<<<dim3(8,16,2), blk, 0, stream>>>(FF, W_ff2, b_ff2, ENC, PART,
      512, 2048, 32768, 8192, 2048L, 1048576L, 512L, 512L, 2, 0);
  reduce_ep<<<dim3(4096), blk, 0, stream>>>(PART, b_ff2, ENC,
      2, 512, 8192, 512L, 512L, 0, 16*128*512, 16);
  // decoder: Z0 = tanh(ENC @ W_d0 + b_d0)   (split-8)
  gemm_skinny<<<dim3(32,1,8), blk, 0, stream>>>(ENC, W_d0, b_d0, Z0, PART,
      2048, 8192, 8192, 2048, 0L, 0L, 0L, 0L, 8, 0);
  reduce_ep<<<dim3(1024), blk, 0, stream>>>(PART, b_d0, Z0,
      8, 2048, 2048, 0L, 0L, 1, 128*2048, 1);
  // Z1 = tanh(Z0 @ W_dmid[0] + b_dmid[0])
  gemm_skinny<<<dim3(32,1,8), blk, 0, stream>>>(Z0, W_dmid, b_dmid, Z1, PART,
      2048, 2048, 2048, 2048, 0L, 0L, 0L, 0L, 8, 0);
  reduce_ep<<<dim3(1024), blk, 0, stream>>>(PART, b_dmid, Z1,
      8, 2048, 2048, 0L, 0L, 1, 128*2048, 1);
  // Z2 = tanh(Z1 @ W_dmid[1] + b_dmid[1])
  gemm_skinny<<<dim3(32,1,8), blk, 0, stream>>>(Z1, W_dmid + 4194304, b_dmid + 2048, Z2, PART,
      2048, 2048, 2048, 2048, 0L, 0L, 0L, 0L, 8, 0);
  reduce_ep<<<dim3(1024), blk, 0, stream>>>(PART, b_dmid + 2048, Z2,
      8, 2048, 2048, 0L, 0L, 1, 128*2048, 1);
  // Y = Z2 @ W_dout + b_dout -> d_out [1,128,1024]
  gemm_skinny<<<dim3(16,1,8), blk, 0, stream>>>(Z2, W_dout, b_dout, (float*)d_out, PART,
      1024, 2048, 2048, 1024, 0L, 0L, 0L, 0L, 8, 0);
  reduce_ep<<<dim3(512), blk, 0, stream>>>(PART, b_dout, (float*)d_out,
      8, 1024, 1024, 0L, 0L, 0, 128*1024, 1);
}